// Round 2
// baseline (3263.452 us; speedup 1.0000x reference)
//
#include <hip/hip_runtime.h>
#include <type_traits>

#define DEV __device__ __forceinline__

typedef _Float16 f16;
typedef __attribute__((ext_vector_type(8))) _Float16 f16x8;
typedef __attribute__((ext_vector_type(4))) float f32x4;

DEV int imin(int a, int b) { return a < b ? a : b; }

// LDS tile byte-swizzle: rows are 128B (64 f16); XOR row&7 into bits 4..6
DEV int swz(int row, int colByte) { return (row * 128 + colByte) ^ ((row & 7) << 4); }

DEV void split2(float x, float y, unsigned& hi, unsigned& lo) {
  f16 hx = (f16)x, hy = (f16)y;
  f16 lx = (f16)(x - (float)hx), ly = (f16)(y - (float)hy);
  hi = (unsigned)__builtin_bit_cast(unsigned short, hx) |
       ((unsigned)__builtin_bit_cast(unsigned short, hy) << 16);
  lo = (unsigned)__builtin_bit_cast(unsigned short, lx) |
       ((unsigned)__builtin_bit_cast(unsigned short, ly) << 16);
}

struct GArgs {
  const void* A; const void* Alo;
  const void* B; const void* Blo;
  const float* Hin; float* Hout;
  f16* O16; f16* O16lo;
  const float* bias;
  const float* rspIn; float* rspOut;
  const float* lnw;
  const int* perm; const float* prob; const int* off;
  int M, K, lda, ldb, ldo;
  long sAz, sBz, sOz;
};

// AM: 0=f16(pair) [M][K]; 1=f32 [M][K]; 2=f32 [M][K]+rms; 3=f32 rms+gather(perm); 4=f32 transpose
// BMD: 0=f16(pair) [N][K]; 1=f32 [K][N] (strided); 2=f32 [N][K]
// CM: 0=f16(pair) store; 1=H update(+rsum); 2=relu->f16 pair (guarded); 3=scatter H += prob*acc (+rsum)
template<int TM,int TN,int WR,int WC,int AM,int BMD,int CM,bool RESID,bool BIAS,bool EXPERT,bool SPL>
__global__ __launch_bounds__(WR*WC*64)
void gk(GArgs a) {
  constexpr int TK = 64;
  constexpr int NT = WR * WC * 64;
  constexpr int WTM = TM / WR, WTN = TN / WC;
  constexpr int FM = WTM / 16, FN = WTN / 16;
  constexpr int UA = (AM == 0) ? (TM * (TK / 8)) / NT : (TM * (TK / 4)) / NT;
  constexpr int UB = (BMD == 0) ? (TN * (TK / 8)) / NT : (TN * (TK / 4)) / NT;
  static_assert((CM != 1 && CM != 3) || WTN == 32, "rsum partials assume 32-col wave tiles");

  __shared__ __align__(16) f16 As[TM * TK];
  __shared__ __align__(16) f16 Bs[TN * TK];
  __shared__ __align__(16) f16 AsL[SPL ? TM * TK : 8];
  __shared__ __align__(16) f16 BsL[SPL ? TN * TK : 8];
  __shared__ float rrlds[(AM == 2 || AM == 3) ? TM : 1];

  const int tid = threadIdx.x;
  const int lane = tid & 63;
  const int wid = tid >> 6;
  const int wr = wid / WC, wc = wid % WC;

  int m0;
  int sEnd = 0x7fffffff;
  const char* Ab = (const char*)a.A;
  const char* AbL = (const char*)a.Alo;
  const char* Bb = (const char*)a.B;
  const char* BbL = (const char*)a.Blo;
  f16* O = a.O16;
  f16* OL = a.O16lo;
  if constexpr (EXPERT) {
    int e = blockIdx.z;
    int o0 = a.off[e], o1 = a.off[e + 1];
    if ((int)blockIdx.y * TM >= o1 - o0) return;  // early-exit before any barrier
    m0 = o0 + blockIdx.y * TM;
    sEnd = o1;
    Bb += (long)e * a.sBz * 4;
  } else {
    m0 = blockIdx.y * TM;
    int z = blockIdx.z;
    Ab += (long)z * a.sAz * 4;
    Bb += (long)z * a.sBz * 4;
    if constexpr (CM == 0) {
      O += (long)z * a.sOz;
      if constexpr (SPL) OL += (long)z * a.sOz;
    }
  }
  const int n0 = blockIdx.x * TN;

  // ---- rms prologue: rr per tile row from 24 col-partials ----
  if constexpr (AM == 2 || AM == 3) {
    if (tid < TM) {
      int s = m0 + tid;
      int row = (AM == 3) ? a.perm[imin(s, a.M - 1)] : imin(s, a.M - 1);
      float ss = 0.f;
      #pragma unroll
      for (int j = 0; j < 24; ++j) ss += a.rspIn[row * 24 + j];
      rrlds[tid] = rsqrtf(ss * (1.f / 768.f) + 1e-6f);
    }
  }

  int arow[UA];
  #pragma unroll
  for (int u = 0; u < UA; ++u) {
    int id = tid + u * NT;
    if constexpr (AM == 0) arow[u] = imin(m0 + (id >> 3), a.M - 1);
    else if constexpr (AM == 3) arow[u] = a.perm[imin(m0 + (id >> 4), a.M - 1)];
    else if constexpr (AM == 4) arow[u] = id % TM;   // local col in source
    else arow[u] = m0 + (id >> 4);
  }

  using ARt = typename std::conditional<AM == 0, int4, float4>::type;
  using BRt = typename std::conditional<BMD == 0, int4, float4>::type;

  auto issueA = [&](ARt* rg, ARt* rl, int k0) {
    #pragma unroll
    for (int u = 0; u < UA; ++u) {
      int id = tid + u * NT;
      if constexpr (AM == 0) {
        int kq = id & 7;
        long off = ((long)arow[u] * a.lda + k0 + kq * 8) * 2;
        rg[u] = *(const int4*)(Ab + off);
        if constexpr (SPL) rl[u] = *(const int4*)(AbL + off);
      } else if constexpr (AM == 4) {
        int kq = id / TM;
        const float* g = (const float*)Ab;
        #pragma unroll
        for (int i = 0; i < 4; ++i)
          ((float*)&rg[u])[i] = g[(long)(k0 + kq * 4 + i) * a.lda + (m0 + arow[u])];
      } else {
        int kq = id & 15;
        rg[u] = *(const float4*)(Ab + ((long)arow[u] * a.lda + k0 + kq * 4) * 4);
      }
    }
  };
  auto commitA = [&](ARt* rg, ARt* rl, int k0) {
    #pragma unroll
    for (int u = 0; u < UA; ++u) {
      int id = tid + u * NT;
      if constexpr (AM == 0) {
        int m = id >> 3, kq = id & 7;
        *(int4*)((char*)As + swz(m, kq * 16)) = rg[u];
        if constexpr (SPL) *(int4*)((char*)AsL + swz(m, kq * 16)) = rl[u];
      } else {
        int m, kq;
        if constexpr (AM == 4) { m = id % TM; kq = id / TM; }
        else { m = id >> 4; kq = id & 15; }
        float4 v = *(float4*)&rg[u];
        if constexpr (AM == 2 || AM == 3) {
          float rr = rrlds[m];
          const float* w = a.lnw + k0 + kq * 4;
          v.x *= rr * w[0]; v.y *= rr * w[1]; v.z *= rr * w[2]; v.w *= rr * w[3];
        }
        if constexpr (SPL) {
          uint2 ph, pl;
          split2(v.x, v.y, ph.x, pl.x);
          split2(v.z, v.w, ph.y, pl.y);
          *(uint2*)((char*)As + swz(m, kq * 8)) = ph;
          *(uint2*)((char*)AsL + swz(m, kq * 8)) = pl;
        } else {
          uint2 p;
          unsigned t;
          split2(v.x, v.y, p.x, t); split2(v.z, v.w, p.y, t);
          *(uint2*)((char*)As + swz(m, kq * 8)) = p;
        }
      }
    }
  };
  auto issueB = [&](BRt* rg, BRt* rl, int k0) {
    #pragma unroll
    for (int u = 0; u < UB; ++u) {
      int id = tid + u * NT;
      if constexpr (BMD == 0) {
        int n = id >> 3, kq = id & 7;
        long off = ((long)(n0 + n) * a.ldb + k0 + kq * 8) * 2;
        rg[u] = *(const int4*)(Bb + off);
        if constexpr (SPL) rl[u] = *(const int4*)(BbL + off);
      } else if constexpr (BMD == 1) {
        int n = id % TN, kq = id / TN;
        const float* g = (const float*)Bb;
        #pragma unroll
        for (int i = 0; i < 4; ++i)
          ((float*)&rg[u])[i] = g[(long)(k0 + kq * 4 + i) * a.ldb + (n0 + n)];
      } else {
        int n = id >> 4, kq = id & 15;
        rg[u] = *(const float4*)(Bb + ((long)(n0 + n) * a.ldb + k0 + kq * 4) * 4);
      }
    }
  };
  auto commitB = [&](BRt* rg, BRt* rl) {
    #pragma unroll
    for (int u = 0; u < UB; ++u) {
      int id = tid + u * NT;
      if constexpr (BMD == 0) {
        int n = id >> 3, kq = id & 7;
        *(int4*)((char*)Bs + swz(n, kq * 16)) = rg[u];
        if constexpr (SPL) *(int4*)((char*)BsL + swz(n, kq * 16)) = rl[u];
      } else {
        int n, kq;
        if constexpr (BMD == 1) { n = id % TN; kq = id / TN; }
        else { n = id >> 4; kq = id & 15; }
        float4 v = *(float4*)&rg[u];
        if constexpr (SPL) {
          uint2 ph, pl;
          split2(v.x, v.y, ph.x, pl.x);
          split2(v.z, v.w, ph.y, pl.y);
          *(uint2*)((char*)Bs + swz(n, kq * 8)) = ph;
          *(uint2*)((char*)BsL + swz(n, kq * 8)) = pl;
        } else {
          uint2 p;
          unsigned t;
          split2(v.x, v.y, p.x, t); split2(v.z, v.w, p.y, t);
          *(uint2*)((char*)Bs + swz(n, kq * 8)) = p;
        }
      }
    }
  };

  f32x4 acc[FM][FN] = {};
  auto compute = [&]() {
    #pragma unroll
    for (int kk = 0; kk < 2; ++kk) {
      const int col2 = (kk * 32 + (lane >> 4) * 8) * 2;
      f16x8 ah[FM], bh[FN];
      #pragma unroll
      for (int i = 0; i < FM; ++i)
        ah[i] = *(const f16x8*)((const char*)As + swz(wr * WTM + i * 16 + (lane & 15), col2));
      #pragma unroll
      for (int j = 0; j < FN; ++j)
        bh[j] = *(const f16x8*)((const char*)Bs + swz(wc * WTN + j * 16 + (lane & 15), col2));
      if constexpr (SPL) {
        f16x8 al[FM], bl[FN];
        #pragma unroll
        for (int i = 0; i < FM; ++i)
          al[i] = *(const f16x8*)((const char*)AsL + swz(wr * WTM + i * 16 + (lane & 15), col2));
        #pragma unroll
        for (int j = 0; j < FN; ++j)
          bl[j] = *(const f16x8*)((const char*)BsL + swz(wc * WTN + j * 16 + (lane & 15), col2));
        #pragma unroll
        for (int i = 0; i < FM; ++i)
          #pragma unroll
          for (int j = 0; j < FN; ++j) {
            f32x4 t = acc[i][j];
            t = __builtin_amdgcn_mfma_f32_16x16x32_f16(al[i], bl[j], t, 0, 0, 0);
            t = __builtin_amdgcn_mfma_f32_16x16x32_f16(al[i], bh[j], t, 0, 0, 0);
            t = __builtin_amdgcn_mfma_f32_16x16x32_f16(ah[i], bl[j], t, 0, 0, 0);
            t = __builtin_amdgcn_mfma_f32_16x16x32_f16(ah[i], bh[j], t, 0, 0, 0);
            acc[i][j] = t;
          }
      } else {
        #pragma unroll
        for (int i = 0; i < FM; ++i)
          #pragma unroll
          for (int j = 0; j < FN; ++j)
            acc[i][j] = __builtin_amdgcn_mfma_f32_16x16x32_f16(ah[i], bh[j], acc[i][j], 0, 0, 0);
      }
    }
  };

  ARt a0[UA], a1[UA], a0l[UA], a1l[UA];
  BRt b0[UB], b1[UB], b0l[UB], b1l[UB];
  const int ns = a.K / TK;
  issueA(a0, a0l, 0); issueB(b0, b0l, 0);
  for (int s0 = 0; s0 < ns; s0 += 2) {
    __syncthreads();
    commitA(a0, a0l, s0 * TK); commitB(b0, b0l);
    if (s0 + 1 < ns) { issueA(a1, a1l, (s0 + 1) * TK); issueB(b1, b1l, (s0 + 1) * TK); }
    __syncthreads();
    compute();
    if (s0 + 1 < ns) {
      __syncthreads();
      commitA(a1, a1l, (s0 + 1) * TK); commitB(b1, b1l);
      if (s0 + 2 < ns) { issueA(a0, a0l, (s0 + 2) * TK); issueB(b0, b0l, (s0 + 2) * TK); }
      __syncthreads();
      compute();
    }
  }

  // ---- epilogue ----
  const int cr = (lane >> 4) * 4;
  const int cc = lane & 15;
  if constexpr (CM == 0 || CM == 2) {
    #pragma unroll
    for (int i = 0; i < FM; ++i) {
      #pragma unroll
      for (int r = 0; r < 4; ++r) {
        int gm = m0 + wr * WTM + i * 16 + cr + r;
        if (gm >= sEnd) continue;
        #pragma unroll
        for (int j = 0; j < FN; ++j) {
          int gn = n0 + wc * WTN + j * 16 + cc;
          float v = acc[i][j][r];
          if constexpr (CM == 2) v = fmaxf(v, 0.f);
          f16 hv = (f16)v;
          O[(long)gm * a.ldo + gn] = hv;
          if constexpr (SPL) OL[(long)gm * a.ldo + gn] = (f16)(v - (float)hv);
        }
      }
    }
  } else {
    #pragma unroll
    for (int i = 0; i < FM; ++i) {
      #pragma unroll
      for (int r = 0; r < 4; ++r) {
        int s = m0 + wr * WTM + i * 16 + cr + r;
        int grow = s;
        float p = 1.f;
        bool ok = true;
        if constexpr (CM == 3) {
          ok = s < sEnd;
          int t = a.perm[imin(s, a.M - 1)];
          grow = t;
          p = a.prob[t];
        }
        float ssum = 0.f;
        #pragma unroll
        for (int j = 0; j < FN; ++j) {
          int gn = n0 + wc * WTN + j * 16 + cc;
          float v = acc[i][j][r];
          if constexpr (CM == 3) v *= p;
          if constexpr (BIAS) v += a.bias[gn];
          if constexpr (RESID) v += a.Hin[(long)grow * 768 + gn];
          if constexpr (CM == 3) v += a.Hin[(long)grow * 768 + gn];
          if (ok) a.Hout[(long)grow * 768 + gn] = v;
          ssum += v * v;
        }
        ssum += __shfl_xor(ssum, 1); ssum += __shfl_xor(ssum, 2);
        ssum += __shfl_xor(ssum, 4); ssum += __shfl_xor(ssum, 8);
        if (ok && (lane & 15) == 0)
          a.rspOut[(long)grow * 24 + ((n0 + wc * WTN) >> 5)] = ssum;
      }
    }
  }
}

// ---- router: one wave per row ----
__global__ __launch_bounds__(256)
void router_k(const float* H, const float* rsp, const float* lnw, const float* rw,
              int* eid, float* prob) {
  int lane = threadIdx.x & 63;
  int row = blockIdx.x * 4 + (threadIdx.x >> 6);
  float ss = 0.f;
  #pragma unroll
  for (int j = 0; j < 24; ++j) ss += rsp[row * 24 + j];
  float rr = rsqrtf(ss * (1.f / 768.f) + 1e-6f);
  float le[8] = {0, 0, 0, 0, 0, 0, 0, 0};
  #pragma unroll
  for (int i = 0; i < 12; ++i) {
    int k = i * 64 + lane;
    float n = H[row * 768 + k] * rr * lnw[k];
    const float* w = rw + k * 8;
    float4 w0 = *(const float4*)w, w1 = *(const float4*)(w + 4);
    le[0] += n * w0.x; le[1] += n * w0.y; le[2] += n * w0.z; le[3] += n * w0.w;
    le[4] += n * w1.x; le[5] += n * w1.y; le[6] += n * w1.z; le[7] += n * w1.w;
  }
  #pragma unroll
  for (int m = 1; m < 64; m <<= 1) {
    #pragma unroll
    for (int e = 0; e < 8; ++e) le[e] += __shfl_xor(le[e], m);
  }
  float mx = le[0]; int am = 0;
  #pragma unroll
  for (int e = 1; e < 8; ++e) if (le[e] > mx) { mx = le[e]; am = e; }
  float den = 0.f;
  #pragma unroll
  for (int e = 0; e < 8; ++e) den += expf(le[e] - mx);
  if (lane == 0) { eid[row] = am; prob[row] = 1.f / den; }
}

__global__ __launch_bounds__(256)
void scan_k(const int* eid, int* off, int* perm) {
  __shared__ int cnt[8], c2[8], offs[9];
  int tid = threadIdx.x;
  if (tid < 8) { cnt[tid] = 0; c2[tid] = 0; }
  __syncthreads();
  for (int t = tid; t < 1024; t += 256) atomicAdd(&cnt[eid[t]], 1);
  __syncthreads();
  if (tid == 0) {
    int acc = 0;
    for (int e = 0; e < 8; ++e) { offs[e] = acc; acc += cnt[e]; }
    offs[8] = acc;
    for (int e = 0; e < 9; ++e) off[e] = offs[e];
  }
  __syncthreads();
  for (int t = tid; t < 1024; t += 256) {
    int e = eid[t];
    int r = atomicAdd(&c2[e], 1);
    perm[offs[e] + r] = t;
  }
}

__global__ __launch_bounds__(256)
void fc_k(const float* H, const float* rsp, const float* lnw, const float* fw,
          const float* fb, float* out) {
  int lane = threadIdx.x & 63;
  int row = blockIdx.x * 4 + (threadIdx.x >> 6);
  float ss = 0.f;
  #pragma unroll
  for (int j = 0; j < 24; ++j) ss += rsp[row * 24 + j];
  float rr = rsqrtf(ss * (1.f / 768.f) + 1e-6f);
  float acc[10] = {0, 0, 0, 0, 0, 0, 0, 0, 0, 0};
  #pragma unroll
  for (int i = 0; i < 12; ++i) {
    int k = i * 64 + lane;
    float n = H[row * 768 + k] * rr * lnw[k];
    const float* w = fw + k * 10;
    #pragma unroll
    for (int c = 0; c < 10; ++c) acc[c] += n * w[c];
  }
  #pragma unroll
  for (int m = 1; m < 64; m <<= 1) {
    #pragma unroll
    for (int c = 0; c < 10; ++c) acc[c] += __shfl_xor(acc[c], m);
  }
  if (lane == 0) {
    #pragma unroll
    for (int c = 0; c < 10; ++c) out[row * 10 + c] = acc[c] + fb[c];
  }
}

extern "C" void kernel_launch(void* const* d_in, const int* in_sizes, int n_in,
                              void* d_out, int out_size, void* d_ws, size_t ws_size,
                              hipStream_t stream) {
  const float* x     = (const float*)d_in[0];
  const float* projw = (const float*)d_in[1];
  const float* projb = (const float*)d_in[2];
  const float* ln1   = (const float*)d_in[3];
  const float* wvp   = (const float*)d_in[4];
  const float* wop   = (const float*)d_in[5];
  const float* ln2   = (const float*)d_in[6];
  const float* dwi   = (const float*)d_in[7];
  const float* dwo   = (const float*)d_in[8];
  const float* rw    = (const float*)d_in[9];
  const float* ewi   = (const float*)d_in[10];
  const float* ewo   = (const float*)d_in[11];
  const float* flnw  = (const float*)d_in[12];
  const float* fcw   = (const float*)d_in[13];
  const float* fcb   = (const float*)d_in[14];

  char* ws = (char*)d_ws;
  float* hA   = (float*)(ws);                        // 1024*768*4   = 3,145,728
  float* hB   = (float*)(ws + 3145728);              // 3,145,728
  f16*   hidH = (f16*)(ws + 6291456);                // 1024*3072*2  = 6,291,456
  f16*   hidL = (f16*)(ws + 12582912);               // 6,291,456
  float* rsp  = (float*)(ws + 18874368);             // 25*1024*24*4 = 2,457,600
  int*   eid  = (int*)(ws + 21331968);
  float* prob = (float*)(ws + 21336064);
  int*   perm = (int*)(ws + 21340160);
  int*   off  = (int*)(ws + 21344256);
  f16*   wctH = (f16*)(ws + 21344768);               // 12*768*768*2 = 14,155,776
  f16*   wctL = (f16*)(ws + 35500544);               // 14,155,776 -> end 49,656,320
  const bool useWct = ws_size >= 49656320u;
  auto slot = [&](int s) { return rsp + (long)s * 1024 * 24; };

  if (useWct) {  // Wc^T[l] = (wv@wo)^T, stored as f16 hi/lo pair: wct[l][n][k]
    GArgs g{}; g.A = wop; g.B = wvp; g.O16 = wctH; g.O16lo = wctL;
    g.M = 768; g.K = 768; g.lda = 768; g.ldb = 768; g.ldo = 768;
    g.sAz = 589824; g.sBz = 589824; g.sOz = 589824;
    gk<64,64,2,2, 4,2,0, false,false,false,true><<<dim3(12,12,12), 256, 0, stream>>>(g);
  }
  { // proj: hA = x @ proj_w + b ; rsum -> slot 0
    GArgs g{}; g.A = x; g.B = projw; g.Hout = hA; g.bias = projb; g.rspOut = slot(0);
    g.M = 1024; g.K = 3072; g.lda = 3072; g.ldb = 768;
    gk<64,64,2,2, 1,1,1, false,true,false,true><<<dim3(12,16,1), 256, 0, stream>>>(g);
  }
  for (int l = 0; l < 12; ++l) {
    if (useWct) { // hB = hA + rmsnorm(hA,ln1) @ Wc[l]
      GArgs g{}; g.A = hA; g.B = wctH + (long)l * 589824; g.Blo = wctL + (long)l * 589824;
      g.Hin = hA; g.Hout = hB;
      g.rspIn = slot(2*l); g.rspOut = slot(2*l+1); g.lnw = ln1 + l * 768;
      g.M = 1024; g.K = 768; g.lda = 768; g.ldb = 768;
      gk<64,64,2,2, 2,0,1, true,false,false,true><<<dim3(12,16,1), 256, 0, stream>>>(g);
    } else {
      { // t = rmsnorm(hA,ln1) @ wv -> hid pair
        GArgs g{}; g.A = hA; g.B = wvp + (long)l * 589824; g.O16 = hidH; g.O16lo = hidL;
        g.rspIn = slot(2*l); g.lnw = ln1 + l * 768;
        g.M = 1024; g.K = 768; g.lda = 768; g.ldb = 768; g.ldo = 768;
        gk<64,64,2,2, 2,1,0, false,false,false,true><<<dim3(12,16,1), 256, 0, stream>>>(g);
      }
      { // hB = hA + t @ wo
        GArgs g{}; g.A = hidH; g.Alo = hidL; g.B = wop + (long)l * 589824;
        g.Hin = hA; g.Hout = hB; g.rspOut = slot(2*l+1);
        g.M = 1024; g.K = 768; g.lda = 768; g.ldb = 768;
        gk<64,64,2,2, 0,1,1, true,false,false,true><<<dim3(12,16,1), 256, 0, stream>>>(g);
      }
    }
    if ((l & 1) == 0) {
      int di = l / 2;
      { // ffn1: hid pair = relu(rmsnorm(hB,ln2) @ dwi)
        GArgs g{}; g.A = hB; g.B = dwi + (long)di * 768 * 3072; g.O16 = hidH; g.O16lo = hidL;
        g.rspIn = slot(2*l+1); g.lnw = ln2 + l * 768;
        g.M = 1024; g.K = 768; g.lda = 768; g.ldb = 3072; g.ldo = 3072;
        gk<64,64,2,2, 2,1,2, false,false,false,true><<<dim3(48,16,1), 256, 0, stream>>>(g);
      }
      { // ffn2: hA = hB + hid @ dwo
        GArgs g{}; g.A = hidH; g.Alo = hidL; g.B = dwo + (long)di * 3072 * 768;
        g.Hin = hB; g.Hout = hA; g.rspOut = slot(2*l+2);
        g.M = 1024; g.K = 3072; g.lda = 3072; g.ldb = 768;
        gk<64,64,2,2, 0,1,1, true,false,false,true><<<dim3(12,16,1), 256, 0, stream>>>(g);
      }
    } else {
      int mi = l / 2;
      router_k<<<dim3(256), 256, 0, stream>>>(hB, slot(2*l+1), ln2 + l * 768,
                                              rw + (long)mi * 768 * 8, eid, prob);
      scan_k<<<dim3(1), 256, 0, stream>>>(eid, off, perm);
      { // egemm1: hid[slot] pair = relu(rmsnorm(hB)[perm[slot]] @ ewi[e])
        GArgs g{}; g.A = hB; g.B = ewi + (long)mi * 8 * 768 * 3072; g.O16 = hidH; g.O16lo = hidL;
        g.rspIn = slot(2*l+1); g.lnw = ln2 + l * 768; g.perm = perm; g.off = off;
        g.M = 1024; g.K = 768; g.lda = 768; g.ldb = 3072; g.ldo = 3072;
        g.sBz = (long)768 * 3072;
        gk<128,64,4,2, 3,1,2, false,false,true,true><<<dim3(48,8,8), 512, 0, stream>>>(g);
      }
      { // egemm2: hA[perm[s]] = hB[perm[s]] + prob * (hid[s] @ ewo[e])
        GArgs g{}; g.A = hidH; g.Alo = hidL; g.B = ewo + (long)mi * 8 * 3072 * 768;
        g.Hin = hB; g.Hout = hA;
        g.rspOut = slot(2*l+2); g.perm = perm; g.prob = prob; g.off = off;
        g.M = 1024; g.K = 3072; g.lda = 3072; g.ldb = 768;
        g.sBz = (long)3072 * 768;
        gk<128,64,4,2, 0,1,3, false,false,true,true><<<dim3(12,8,8), 512, 0, stream>>>(g);
      }
    }
  }
  fc_k<<<dim3(256), 256, 0, stream>>>(hA, slot(24), flnw, fcw, fcb, (float*)d_out);
}

// Round 3
// 2433.032 us; speedup vs baseline: 1.3413x; 1.3413x over previous
//
#include <hip/hip_runtime.h>
#include <type_traits>

#define DEV __device__ __forceinline__

typedef _Float16 f16;
typedef __attribute__((ext_vector_type(8))) _Float16 f16x8;
typedef __attribute__((ext_vector_type(4))) float f32x4;

DEV int imin(int a, int b) { return a < b ? a : b; }

// LDS tile byte-swizzle: rows are 128B (64 f16); XOR row&7 into bits 4..6
DEV int swz(int row, int colByte) { return (row * 128 + colByte) ^ ((row & 7) << 4); }

DEV void split2(float x, float y, unsigned& hi, unsigned& lo) {
  f16 hx = (f16)x, hy = (f16)y;
  f16 lx = (f16)(x - (float)hx), ly = (f16)(y - (float)hy);
  hi = (unsigned)__builtin_bit_cast(unsigned short, hx) |
       ((unsigned)__builtin_bit_cast(unsigned short, hy) << 16);
  lo = (unsigned)__builtin_bit_cast(unsigned short, lx) |
       ((unsigned)__builtin_bit_cast(unsigned short, ly) << 16);
}

struct GArgs {
  const void* A; const void* Alo;
  const void* B; const void* Blo;
  const float* Hin; float* Hout;
  f16* O16; f16* O16lo;
  const float* bias;
  const float* rspIn; float* rspOut;
  const float* lnw;
  const int* perm; const float* prob; const int* off;
  int M, K, lda, ldb, ldo;
  long sAz, sBz, sOz;
  long zA, zB, zH;   // per-K-chunk strides: bytes (A), bytes (B), elements (Hout slab)
  int KS;            // split-K factor (z = e*KS + kc)
};

// AM: 0=f16(pair) [M][K]; 1=f32 [M][K]; 2=f32 [M][K]+rms; 3=f32 rms+gather(perm); 4=f32 transpose
// BMD: 0=f16(pair) [N][K]; 1=f32 [K][N] (strided); 2=f32 [N][K]
// CM: 0=f16(pair) store; 1=H update(+rsum); 2=relu->f16 pair (guarded); 3=scatter; 4=f32 partial slab
template<int TM,int TN,int WR,int WC,int AM,int BMD,int CM,bool RESID,bool BIAS,bool EXPERT,bool SPL>
__global__ __launch_bounds__(WR*WC*64)
void gk(GArgs a) {
  constexpr int TK = 64;
  constexpr int NT = WR * WC * 64;
  constexpr int WTM = TM / WR, WTN = TN / WC;
  constexpr int FM = WTM / 16, FN = WTN / 16;
  constexpr int UA = (AM == 0) ? (TM * (TK / 8)) / NT : (TM * (TK / 4)) / NT;
  constexpr int UB = (BMD == 0) ? (TN * (TK / 8)) / NT : (TN * (TK / 4)) / NT;
  static_assert((CM != 1 && CM != 3) || WTN == 32, "rsum partials assume 32-col wave tiles");

  __shared__ __align__(16) f16 As[TM * TK];
  __shared__ __align__(16) f16 Bs[TN * TK];
  __shared__ __align__(16) f16 AsL[SPL ? TM * TK : 8];
  __shared__ __align__(16) f16 BsL[SPL ? TN * TK : 8];
  __shared__ float rrlds[(AM == 2 || AM == 3) ? TM : 1];

  const int tid = threadIdx.x;
  const int lane = tid & 63;
  const int wid = tid >> 6;
  const int wr = wid / WC, wc = wid % WC;

  int m0;
  int sEnd = 0x7fffffff;
  const char* Ab = (const char*)a.A;
  const char* AbL = (const char*)a.Alo;
  const char* Bb = (const char*)a.B;
  const char* BbL = (const char*)a.Blo;
  f16* O = a.O16;
  f16* OL = a.O16lo;
  float* HoutP = a.Hout;
  {
    int z = blockIdx.z;
    int e = z / a.KS;
    int kc = z - e * a.KS;
    if constexpr (EXPERT) {
      int o0 = a.off[e], o1 = a.off[e + 1];
      if ((int)blockIdx.y * TM >= o1 - o0) return;  // early-exit before any barrier
      m0 = o0 + blockIdx.y * TM;
      sEnd = o1;
      Bb += (long)e * a.sBz * 4 + (long)kc * a.zB;
      Ab += (long)kc * a.zA;
      AbL += (long)kc * a.zA;
    } else {
      m0 = blockIdx.y * TM;
      Ab += (long)e * a.sAz * 4 + (long)kc * a.zA;
      AbL += (long)kc * a.zA;
      Bb += (long)e * a.sBz * 4 + (long)kc * a.zB;
      if constexpr (CM == 0) {
        O += (long)e * a.sOz;
        if constexpr (SPL) OL += (long)e * a.sOz;
      }
    }
    if constexpr (CM == 4) HoutP += (long)kc * a.zH;
  }
  const int n0 = blockIdx.x * TN;

  // ---- rms prologue: rr per tile row from 24 col-partials ----
  if constexpr (AM == 2 || AM == 3) {
    if (tid < TM) {
      int s = m0 + tid;
      int row = (AM == 3) ? a.perm[imin(s, a.M - 1)] : imin(s, a.M - 1);
      float ss = 0.f;
      #pragma unroll
      for (int j = 0; j < 24; ++j) ss += a.rspIn[row * 24 + j];
      rrlds[tid] = rsqrtf(ss * (1.f / 768.f) + 1e-6f);
    }
  }

  int arow[UA];
  #pragma unroll
  for (int u = 0; u < UA; ++u) {
    int id = tid + u * NT;
    if constexpr (AM == 0) arow[u] = imin(m0 + (id >> 3), a.M - 1);
    else if constexpr (AM == 3) arow[u] = a.perm[imin(m0 + (id >> 4), a.M - 1)];
    else if constexpr (AM == 4) arow[u] = id % TM;   // local col in source
    else arow[u] = imin(m0 + (id >> 4), a.M - 1);
  }

  using ARt = typename std::conditional<AM == 0, int4, float4>::type;
  using BRt = typename std::conditional<BMD == 0, int4, float4>::type;

  auto issueA = [&](ARt* rg, ARt* rl, int k0) {
    #pragma unroll
    for (int u = 0; u < UA; ++u) {
      int id = tid + u * NT;
      if constexpr (AM == 0) {
        int kq = id & 7;
        long off = ((long)arow[u] * a.lda + k0 + kq * 8) * 2;
        rg[u] = *(const int4*)(Ab + off);
        if constexpr (SPL) rl[u] = *(const int4*)(AbL + off);
      } else if constexpr (AM == 4) {
        int kq = id / TM;
        const float* g = (const float*)Ab;
        #pragma unroll
        for (int i = 0; i < 4; ++i)
          ((float*)&rg[u])[i] = g[(long)(k0 + kq * 4 + i) * a.lda + (m0 + arow[u])];
      } else {
        int kq = id & 15;
        rg[u] = *(const float4*)(Ab + ((long)arow[u] * a.lda + k0 + kq * 4) * 4);
      }
    }
  };
  auto commitA = [&](ARt* rg, ARt* rl, int k0) {
    #pragma unroll
    for (int u = 0; u < UA; ++u) {
      int id = tid + u * NT;
      if constexpr (AM == 0) {
        int m = id >> 3, kq = id & 7;
        *(int4*)((char*)As + swz(m, kq * 16)) = rg[u];
        if constexpr (SPL) *(int4*)((char*)AsL + swz(m, kq * 16)) = rl[u];
      } else {
        int m, kq;
        if constexpr (AM == 4) { m = id % TM; kq = id / TM; }
        else { m = id >> 4; kq = id & 15; }
        float4 v = *(float4*)&rg[u];
        if constexpr (AM == 2 || AM == 3) {
          float rr = rrlds[m];
          const float* w = a.lnw + k0 + kq * 4;
          v.x *= rr * w[0]; v.y *= rr * w[1]; v.z *= rr * w[2]; v.w *= rr * w[3];
        }
        if constexpr (SPL) {
          uint2 ph, pl;
          split2(v.x, v.y, ph.x, pl.x);
          split2(v.z, v.w, ph.y, pl.y);
          *(uint2*)((char*)As + swz(m, kq * 8)) = ph;
          *(uint2*)((char*)AsL + swz(m, kq * 8)) = pl;
        } else {
          uint2 p;
          unsigned t;
          split2(v.x, v.y, p.x, t); split2(v.z, v.w, p.y, t);
          *(uint2*)((char*)As + swz(m, kq * 8)) = p;
        }
      }
    }
  };
  auto issueB = [&](BRt* rg, BRt* rl, int k0) {
    #pragma unroll
    for (int u = 0; u < UB; ++u) {
      int id = tid + u * NT;
      if constexpr (BMD == 0) {
        int n = id >> 3, kq = id & 7;
        long off = ((long)(n0 + n) * a.ldb + k0 + kq * 8) * 2;
        rg[u] = *(const int4*)(Bb + off);
        if constexpr (SPL) rl[u] = *(const int4*)(BbL + off);
      } else if constexpr (BMD == 1) {
        int n = id % TN, kq = id / TN;
        const float* g = (const float*)Bb;
        #pragma unroll
        for (int i = 0; i < 4; ++i)
          ((float*)&rg[u])[i] = g[(long)(k0 + kq * 4 + i) * a.ldb + (n0 + n)];
      } else {
        int n = id >> 4, kq = id & 15;
        rg[u] = *(const float4*)(Bb + ((long)(n0 + n) * a.ldb + k0 + kq * 4) * 4);
      }
    }
  };
  auto commitB = [&](BRt* rg, BRt* rl) {
    #pragma unroll
    for (int u = 0; u < UB; ++u) {
      int id = tid + u * NT;
      if constexpr (BMD == 0) {
        int n = id >> 3, kq = id & 7;
        *(int4*)((char*)Bs + swz(n, kq * 16)) = rg[u];
        if constexpr (SPL) *(int4*)((char*)BsL + swz(n, kq * 16)) = rl[u];
      } else {
        int n, kq;
        if constexpr (BMD == 1) { n = id % TN; kq = id / TN; }
        else { n = id >> 4; kq = id & 15; }
        float4 v = *(float4*)&rg[u];
        if constexpr (SPL) {
          uint2 ph, pl;
          split2(v.x, v.y, ph.x, pl.x);
          split2(v.z, v.w, ph.y, pl.y);
          *(uint2*)((char*)Bs + swz(n, kq * 8)) = ph;
          *(uint2*)((char*)BsL + swz(n, kq * 8)) = pl;
        } else {
          uint2 p;
          unsigned t;
          split2(v.x, v.y, p.x, t); split2(v.z, v.w, p.y, t);
          *(uint2*)((char*)Bs + swz(n, kq * 8)) = p;
        }
      }
    }
  };

  f32x4 acc[FM][FN] = {};
  auto compute = [&]() {
    #pragma unroll
    for (int kk = 0; kk < 2; ++kk) {
      const int col2 = (kk * 32 + (lane >> 4) * 8) * 2;
      f16x8 ah[FM], bh[FN];
      #pragma unroll
      for (int i = 0; i < FM; ++i)
        ah[i] = *(const f16x8*)((const char*)As + swz(wr * WTM + i * 16 + (lane & 15), col2));
      #pragma unroll
      for (int j = 0; j < FN; ++j)
        bh[j] = *(const f16x8*)((const char*)Bs + swz(wc * WTN + j * 16 + (lane & 15), col2));
      if constexpr (SPL) {
        f16x8 al[FM], bl[FN];
        #pragma unroll
        for (int i = 0; i < FM; ++i)
          al[i] = *(const f16x8*)((const char*)AsL + swz(wr * WTM + i * 16 + (lane & 15), col2));
        #pragma unroll
        for (int j = 0; j < FN; ++j)
          bl[j] = *(const f16x8*)((const char*)BsL + swz(wc * WTN + j * 16 + (lane & 15), col2));
        #pragma unroll
        for (int i = 0; i < FM; ++i)
          #pragma unroll
          for (int j = 0; j < FN; ++j) {
            f32x4 t = acc[i][j];
            t = __builtin_amdgcn_mfma_f32_16x16x32_f16(al[i], bl[j], t, 0, 0, 0);
            t = __builtin_amdgcn_mfma_f32_16x16x32_f16(al[i], bh[j], t, 0, 0, 0);
            t = __builtin_amdgcn_mfma_f32_16x16x32_f16(ah[i], bl[j], t, 0, 0, 0);
            t = __builtin_amdgcn_mfma_f32_16x16x32_f16(ah[i], bh[j], t, 0, 0, 0);
            acc[i][j] = t;
          }
      } else {
        #pragma unroll
        for (int i = 0; i < FM; ++i)
          #pragma unroll
          for (int j = 0; j < FN; ++j)
            acc[i][j] = __builtin_amdgcn_mfma_f32_16x16x32_f16(ah[i], bh[j], acc[i][j], 0, 0, 0);
      }
    }
  };

  ARt a0[UA], a1[UA], a0l[UA], a1l[UA];
  BRt b0[UB], b1[UB], b0l[UB], b1l[UB];
  const int ns = a.K / TK;
  issueA(a0, a0l, 0); issueB(b0, b0l, 0);
  for (int s0 = 0; s0 < ns; s0 += 2) {
    __syncthreads();
    commitA(a0, a0l, s0 * TK); commitB(b0, b0l);
    if (s0 + 1 < ns) { issueA(a1, a1l, (s0 + 1) * TK); issueB(b1, b1l, (s0 + 1) * TK); }
    __syncthreads();
    compute();
    if (s0 + 1 < ns) {
      __syncthreads();
      commitA(a1, a1l, (s0 + 1) * TK); commitB(b1, b1l);
      if (s0 + 2 < ns) { issueA(a0, a0l, (s0 + 2) * TK); issueB(b0, b0l, (s0 + 2) * TK); }
      __syncthreads();
      compute();
    }
  }

  // ---- epilogue ----
  const int cr = (lane >> 4) * 4;
  const int cc = lane & 15;
  if constexpr (CM == 0 || CM == 2) {
    #pragma unroll
    for (int i = 0; i < FM; ++i) {
      #pragma unroll
      for (int r = 0; r < 4; ++r) {
        int gm = m0 + wr * WTM + i * 16 + cr + r;
        if (gm >= sEnd) continue;
        #pragma unroll
        for (int j = 0; j < FN; ++j) {
          int gn = n0 + wc * WTN + j * 16 + cc;
          float v = acc[i][j][r];
          if constexpr (CM == 2) v = fmaxf(v, 0.f);
          f16 hv = (f16)v;
          O[(long)gm * a.ldo + gn] = hv;
          if constexpr (SPL) OL[(long)gm * a.ldo + gn] = (f16)(v - (float)hv);
        }
      }
    }
  } else if constexpr (CM == 4) {
    #pragma unroll
    for (int i = 0; i < FM; ++i) {
      #pragma unroll
      for (int r = 0; r < 4; ++r) {
        int s = m0 + wr * WTM + i * 16 + cr + r;
        if (s >= sEnd || s >= a.M) continue;
        #pragma unroll
        for (int j = 0; j < FN; ++j) {
          int gn = n0 + wc * WTN + j * 16 + cc;
          HoutP[(long)s * a.ldo + gn] = acc[i][j][r];
        }
      }
    }
  } else {
    #pragma unroll
    for (int i = 0; i < FM; ++i) {
      #pragma unroll
      for (int r = 0; r < 4; ++r) {
        int s = m0 + wr * WTM + i * 16 + cr + r;
        int grow = s;
        float p = 1.f;
        bool ok = true;
        if constexpr (CM == 3) {
          ok = s < sEnd;
          int t = a.perm[imin(s, a.M - 1)];
          grow = t;
          p = a.prob[t];
        }
        float ssum = 0.f;
        #pragma unroll
        for (int j = 0; j < FN; ++j) {
          int gn = n0 + wc * WTN + j * 16 + cc;
          float v = acc[i][j][r];
          if constexpr (CM == 3) v *= p;
          if constexpr (BIAS) v += a.bias[gn];
          if constexpr (RESID) v += a.Hin[(long)grow * 768 + gn];
          if constexpr (CM == 3) v += a.Hin[(long)grow * 768 + gn];
          if (ok) HoutP[(long)grow * 768 + gn] = v;
          ssum += v * v;
        }
        ssum += __shfl_xor(ssum, 1); ssum += __shfl_xor(ssum, 2);
        ssum += __shfl_xor(ssum, 4); ssum += __shfl_xor(ssum, 8);
        if (ok && (lane & 15) == 0)
          a.rspOut[(long)grow * 24 + ((n0 + wc * WTN) >> 5)] = ssum;
      }
    }
  }
}

// ---- split-K reduce: out[row] = p*(s0+s1+s2+s3) [+bias] [+Hin[row]], + rsum partials ----
__global__ __launch_bounds__(256)
void red_k(const float* slab, long sst, const int* perm, const float* prob,
           const float* Hin, const float* bias, float* Hout, float* rsp) {
  int lane = threadIdx.x & 63;
  int s = blockIdx.x * 4 + (threadIdx.x >> 6);
  int row = perm ? perm[s] : s;
  float p = prob ? prob[row] : 1.f;
  #pragma unroll
  for (int p3 = 0; p3 < 3; ++p3) {
    int c = p3 * 256 + lane * 4;
    float4 v = *(const float4*)(slab + (long)s * 768 + c);
    float4 v1 = *(const float4*)(slab + sst + (long)s * 768 + c);
    float4 v2 = *(const float4*)(slab + 2 * sst + (long)s * 768 + c);
    float4 v3 = *(const float4*)(slab + 3 * sst + (long)s * 768 + c);
    v.x = (v.x + v1.x) + (v2.x + v3.x); v.y = (v.y + v1.y) + (v2.y + v3.y);
    v.z = (v.z + v1.z) + (v2.z + v3.z); v.w = (v.w + v1.w) + (v2.w + v3.w);
    v.x *= p; v.y *= p; v.z *= p; v.w *= p;
    if (bias) {
      const float4 b = *(const float4*)(bias + c);
      v.x += b.x; v.y += b.y; v.z += b.z; v.w += b.w;
    }
    if (Hin) {
      const float4 h = *(const float4*)(Hin + (long)row * 768 + c);
      v.x += h.x; v.y += h.y; v.z += h.z; v.w += h.w;
    }
    *(float4*)(Hout + (long)row * 768 + c) = v;
    float ss = v.x * v.x + v.y * v.y + v.z * v.z + v.w * v.w;
    ss += __shfl_xor(ss, 1); ss += __shfl_xor(ss, 2); ss += __shfl_xor(ss, 4);
    if ((lane & 7) == 0) rsp[(long)row * 24 + p3 * 8 + (lane >> 3)] = ss;
  }
}

// ---- router: one wave per row ----
__global__ __launch_bounds__(256)
void router_k(const float* H, const float* rsp, const float* lnw, const float* rw,
              int* eid, float* prob) {
  int lane = threadIdx.x & 63;
  int row = blockIdx.x * 4 + (threadIdx.x >> 6);
  float ss = 0.f;
  #pragma unroll
  for (int j = 0; j < 24; ++j) ss += rsp[row * 24 + j];
  float rr = rsqrtf(ss * (1.f / 768.f) + 1e-6f);
  float le[8] = {0, 0, 0, 0, 0, 0, 0, 0};
  #pragma unroll
  for (int i = 0; i < 12; ++i) {
    int k = i * 64 + lane;
    float n = H[row * 768 + k] * rr * lnw[k];
    const float* w = rw + k * 8;
    float4 w0 = *(const float4*)w, w1 = *(const float4*)(w + 4);
    le[0] += n * w0.x; le[1] += n * w0.y; le[2] += n * w0.z; le[3] += n * w0.w;
    le[4] += n * w1.x; le[5] += n * w1.y; le[6] += n * w1.z; le[7] += n * w1.w;
  }
  #pragma unroll
  for (int m = 1; m < 64; m <<= 1) {
    #pragma unroll
    for (int e = 0; e < 8; ++e) le[e] += __shfl_xor(le[e], m);
  }
  float mx = le[0]; int am = 0;
  #pragma unroll
  for (int e = 1; e < 8; ++e) if (le[e] > mx) { mx = le[e]; am = e; }
  float den = 0.f;
  #pragma unroll
  for (int e = 0; e < 8; ++e) den += expf(le[e] - mx);
  if (lane == 0) { eid[row] = am; prob[row] = 1.f / den; }
}

__global__ __launch_bounds__(256)
void scan_k(const int* eid, int* off, int* perm) {
  __shared__ int cnt[8], c2[8], offs[9];
  int tid = threadIdx.x;
  if (tid < 8) { cnt[tid] = 0; c2[tid] = 0; }
  __syncthreads();
  for (int t = tid; t < 1024; t += 256) atomicAdd(&cnt[eid[t]], 1);
  __syncthreads();
  if (tid == 0) {
    int acc = 0;
    for (int e = 0; e < 8; ++e) { offs[e] = acc; acc += cnt[e]; }
    offs[8] = acc;
    for (int e = 0; e < 9; ++e) off[e] = offs[e];
  }
  __syncthreads();
  for (int t = tid; t < 1024; t += 256) {
    int e = eid[t];
    int r = atomicAdd(&c2[e], 1);
    perm[offs[e] + r] = t;
  }
}

__global__ __launch_bounds__(256)
void fc_k(const float* H, const float* rsp, const float* lnw, const float* fw,
          const float* fb, float* out) {
  int lane = threadIdx.x & 63;
  int row = blockIdx.x * 4 + (threadIdx.x >> 6);
  float ss = 0.f;
  #pragma unroll
  for (int j = 0; j < 24; ++j) ss += rsp[row * 24 + j];
  float rr = rsqrtf(ss * (1.f / 768.f) + 1e-6f);
  float acc[10] = {0, 0, 0, 0, 0, 0, 0, 0, 0, 0};
  #pragma unroll
  for (int i = 0; i < 12; ++i) {
    int k = i * 64 + lane;
    float n = H[row * 768 + k] * rr * lnw[k];
    const float* w = fw + k * 10;
    #pragma unroll
    for (int c = 0; c < 10; ++c) acc[c] += n * w[c];
  }
  #pragma unroll
  for (int m = 1; m < 64; m <<= 1) {
    #pragma unroll
    for (int c = 0; c < 10; ++c) acc[c] += __shfl_xor(acc[c], m);
  }
  if (lane == 0) {
    #pragma unroll
    for (int c = 0; c < 10; ++c) out[row * 10 + c] = acc[c] + fb[c];
  }
}

extern "C" void kernel_launch(void* const* d_in, const int* in_sizes, int n_in,
                              void* d_out, int out_size, void* d_ws, size_t ws_size,
                              hipStream_t stream) {
  const float* x     = (const float*)d_in[0];
  const float* projw = (const float*)d_in[1];
  const float* projb = (const float*)d_in[2];
  const float* ln1   = (const float*)d_in[3];
  const float* wvp   = (const float*)d_in[4];
  const float* wop   = (const float*)d_in[5];
  const float* ln2   = (const float*)d_in[6];
  const float* dwi   = (const float*)d_in[7];
  const float* dwo   = (const float*)d_in[8];
  const float* rw    = (const float*)d_in[9];
  const float* ewi   = (const float*)d_in[10];
  const float* ewo   = (const float*)d_in[11];
  const float* flnw  = (const float*)d_in[12];
  const float* fcw   = (const float*)d_in[13];
  const float* fcb   = (const float*)d_in[14];

  char* ws = (char*)d_ws;
  float* hA   = (float*)(ws);                        // 3,145,728
  float* hB   = (float*)(ws + 3145728);              // 3,145,728
  f16*   hidH = (f16*)(ws + 6291456);                // 6,291,456
  f16*   hidL = (f16*)(ws + 12582912);               // 6,291,456
  float* rsp  = (float*)(ws + 18874368);             // 2,457,600
  int*   eid  = (int*)(ws + 21331968);
  float* prob = (float*)(ws + 21336064);
  int*   perm = (int*)(ws + 21340160);
  int*   off  = (int*)(ws + 21344256);
  float* slab = (float*)(ws + 21344768);             // 4*1024*768*4 = 12,582,912
  f16*   wctH = (f16*)(ws + 33927680);               // 14,155,776
  f16*   wctL = (f16*)(ws + 48083456);               // 14,155,776 -> end 62,239,232
  if (ws_size < 33927680u) return;
  const bool useWct = ws_size >= 62239232u;
  auto slot = [&](int s) { return rsp + (long)s * 1024 * 24; };
  const long SST = 1024 * 768;

  if (useWct) {  // Wc^T[l] = (wv@wo)^T as f16 hi/lo pair: wct[l][n][k]
    GArgs g{}; g.A = wop; g.B = wvp; g.O16 = wctH; g.O16lo = wctL; g.KS = 1;
    g.M = 768; g.K = 768; g.lda = 768; g.ldb = 768; g.ldo = 768;
    g.sAz = 589824; g.sBz = 589824; g.sOz = 589824;
    gk<64,64,2,2, 4,2,0, false,false,false,true><<<dim3(12,12,12), 256, 0, stream>>>(g);
  }
  { // proj split-K=4: slab[kc] = x[:, kc] @ proj_w[kc, :]
    GArgs g{}; g.A = x; g.B = projw; g.Hout = slab; g.KS = 4;
    g.M = 1024; g.K = 768; g.lda = 3072; g.ldb = 768; g.ldo = 768;
    g.zA = 768 * 4; g.zB = (long)768 * 768 * 4; g.zH = SST;
    gk<64,64,2,2, 1,1,4, false,false,false,true><<<dim3(12,16,4), 256, 0, stream>>>(g);
    red_k<<<dim3(256), 256, 0, stream>>>(slab, SST, nullptr, nullptr, nullptr, projb, hA, slot(0));
  }
  for (int l = 0; l < 12; ++l) {
    if (useWct) { // attn: hB = hA + rmsnorm(hA,ln1) @ Wc[l]
      GArgs g{}; g.A = hA; g.B = wctH + (long)l * 589824; g.Blo = wctL + (long)l * 589824;
      g.Hin = hA; g.Hout = hB; g.KS = 1;
      g.rspIn = slot(2*l); g.rspOut = slot(2*l+1); g.lnw = ln1 + l * 768;
      g.M = 1024; g.K = 768; g.lda = 768; g.ldb = 768;
      gk<32,64,2,2, 2,0,1, true,false,false,true><<<dim3(12,32,1), 256, 0, stream>>>(g);
    } else {
      { // t = rmsnorm(hA,ln1) @ wv -> hid pair
        GArgs g{}; g.A = hA; g.B = wvp + (long)l * 589824; g.O16 = hidH; g.O16lo = hidL;
        g.rspIn = slot(2*l); g.lnw = ln1 + l * 768; g.KS = 1;
        g.M = 1024; g.K = 768; g.lda = 768; g.ldb = 768; g.ldo = 768;
        gk<64,64,2,2, 2,1,0, false,false,false,true><<<dim3(12,16,1), 256, 0, stream>>>(g);
      }
      { // hB = hA + t @ wo
        GArgs g{}; g.A = hidH; g.Alo = hidL; g.B = wop + (long)l * 589824;
        g.Hin = hA; g.Hout = hB; g.rspOut = slot(2*l+1); g.KS = 1;
        g.M = 1024; g.K = 768; g.lda = 768; g.ldb = 768;
        gk<64,64,2,2, 0,1,1, true,false,false,true><<<dim3(12,16,1), 256, 0, stream>>>(g);
      }
    }
    if ((l & 1) == 0) {
      int di = l / 2;
      { // ffn1: hid pair = relu(rmsnorm(hB,ln2) @ dwi)
        GArgs g{}; g.A = hB; g.B = dwi + (long)di * 768 * 3072; g.O16 = hidH; g.O16lo = hidL;
        g.rspIn = slot(2*l+1); g.lnw = ln2 + l * 768; g.KS = 1;
        g.M = 1024; g.K = 768; g.lda = 768; g.ldb = 3072; g.ldo = 3072;
        gk<64,64,2,2, 2,1,2, false,false,false,true><<<dim3(48,16,1), 256, 0, stream>>>(g);
      }
      { // ffn2 split-K=4 into slabs
        GArgs g{}; g.A = hidH; g.Alo = hidL; g.B = dwo + (long)di * 3072 * 768;
        g.Hout = slab; g.KS = 4;
        g.M = 1024; g.K = 768; g.lda = 3072; g.ldb = 768; g.ldo = 768;
        g.zA = 768 * 2; g.zB = (long)768 * 768 * 4; g.zH = SST;
        gk<64,64,2,2, 0,1,4, false,false,false,true><<<dim3(12,16,4), 256, 0, stream>>>(g);
        red_k<<<dim3(256), 256, 0, stream>>>(slab, SST, nullptr, nullptr, hB, nullptr, hA, slot(2*l+2));
      }
    } else {
      int mi = l / 2;
      router_k<<<dim3(256), 256, 0, stream>>>(hB, slot(2*l+1), ln2 + l * 768,
                                              rw + (long)mi * 768 * 8, eid, prob);
      scan_k<<<dim3(1), 256, 0, stream>>>(eid, off, perm);
      { // egemm1: hid[slot] pair = relu(rmsnorm(hB)[perm[slot]] @ ewi[e])
        GArgs g{}; g.A = hB; g.B = ewi + (long)mi * 8 * 768 * 3072; g.O16 = hidH; g.O16lo = hidL;
        g.rspIn = slot(2*l+1); g.lnw = ln2 + l * 768; g.perm = perm; g.off = off; g.KS = 1;
        g.M = 1024; g.K = 768; g.lda = 768; g.ldb = 3072; g.ldo = 3072;
        g.sBz = (long)768 * 3072;
        gk<64,64,2,2, 3,1,2, false,false,true,true><<<dim3(48,16,8), 256, 0, stream>>>(g);
      }
      { // egemm2 split-K=4: slab[kc][slot] = hid[slot, kc] @ ewo[e][kc, :]
        GArgs g{}; g.A = hidH; g.Alo = hidL; g.B = ewo + (long)mi * 8 * 3072 * 768;
        g.Hout = slab; g.off = off; g.KS = 4;
        g.M = 1024; g.K = 768; g.lda = 3072; g.ldb = 768; g.ldo = 768;
        g.sBz = (long)3072 * 768; g.zA = 768 * 2; g.zB = (long)768 * 768 * 4; g.zH = SST;
        gk<64,64,2,2, 0,1,4, false,false,true,true><<<dim3(12,16,32), 256, 0, stream>>>(g);
        red_k<<<dim3(256), 256, 0, stream>>>(slab, SST, perm, prob, hB, nullptr, hA, slot(2*l+2));
      }
    }
  }
  fc_k<<<dim3(256), 256, 0, stream>>>(hA, slot(24), flnw, fcw, fcb, (float*)d_out);
}

// Round 4
// 1745.241 us; speedup vs baseline: 1.8699x; 1.3941x over previous
//
#include <hip/hip_runtime.h>
#include <type_traits>

#define DEV __device__ __forceinline__

typedef _Float16 f16;
typedef __attribute__((ext_vector_type(8))) _Float16 f16x8;
typedef __attribute__((ext_vector_type(4))) float f32x4;

constexpr int NP = 48;  // rms sum-of-squares partials per row (16 cols each)

DEV int imin(int a, int b) { return a < b ? a : b; }

// LDS tile byte-swizzle: rows are 128B (64 f16); XOR row&7 into bits 4..6
DEV int swz(int row, int colByte) { return (row * 128 + colByte) ^ ((row & 7) << 4); }

DEV void split2(float x, float y, unsigned& hi, unsigned& lo) {
  f16 hx = (f16)x, hy = (f16)y;
  f16 lx = (f16)(x - (float)hx), ly = (f16)(y - (float)hy);
  hi = (unsigned)__builtin_bit_cast(unsigned short, hx) |
       ((unsigned)__builtin_bit_cast(unsigned short, hy) << 16);
  lo = (unsigned)__builtin_bit_cast(unsigned short, lx) |
       ((unsigned)__builtin_bit_cast(unsigned short, ly) << 16);
}

struct GArgs {
  const void* A; const void* Alo;
  const void* B; const void* Blo;
  const float* Hin; float* Hout;
  f16* O16; f16* O16lo;
  const float* bias;
  const float* rspIn; float* rspOut;
  const float* lnw;
  const int* perm; const float* prob; const int* off;
  int M, K, lda, ldb, ldo;
  long sAz, sBz, sOz;
  long zA, zB, zH;   // per-K-chunk strides: bytes (A), bytes (B), elements (Hout slab)
  int KS;            // split-K factor (z = e*KS + kc)
};

// AM: 0=f16(pair) [M][K]; 1=f32 [M][K]; 2=f32 [M][K]+rms; 3=f32 rms+gather(perm); 4=f32 transpose
// BMD: 0=f16(pair) [N][K]; 1=f32 [K][N] (strided); 2=f32 [N][K]
// CM: 0=f16(pair) store; 1=H update(+rsum); 2=relu->f16 pair (guarded); 3=scatter; 4=f32 partial slab
template<int TM,int TN,int WR,int WC,int AM,int BMD,int CM,bool RESID,bool BIAS,bool EXPERT,bool SPL>
__global__ __launch_bounds__(256, 4)
void gk(GArgs a) {
  constexpr int TK = 64;
  constexpr int NT = 256;
  static_assert(WR * WC == 4, "4 waves per block");
  constexpr int WTM = TM / WR, WTN = TN / WC;
  constexpr int FM = WTM / 16, FN = WTN / 16;
  constexpr int UA = (AM == 0) ? (TM * (TK / 8)) / NT : (TM * (TK / 4)) / NT;
  constexpr int UB = (BMD == 0) ? (TN * (TK / 8)) / NT : (TN * (TK / 4)) / NT;

  __shared__ __align__(16) f16 As[2 * TM * TK];
  __shared__ __align__(16) f16 Bs[2 * TN * TK];
  __shared__ __align__(16) f16 AsL[SPL ? 2 * TM * TK : 8];
  __shared__ __align__(16) f16 BsL[SPL ? 2 * TN * TK : 8];
  __shared__ float rrlds[(AM == 2 || AM == 3) ? TM : 1];

  const int tid = threadIdx.x;
  const int lane = tid & 63;
  const int wid = tid >> 6;
  const int wr = wid / WC, wc = wid % WC;

  int m0;
  int sEnd = 0x7fffffff;
  const char* Ab = (const char*)a.A;
  const char* AbL = (const char*)a.Alo;
  const char* Bb = (const char*)a.B;
  const char* BbL = (const char*)a.Blo;
  f16* O = a.O16;
  f16* OL = a.O16lo;
  float* HoutP = a.Hout;
  {
    int z = blockIdx.z;
    int e = z / a.KS;
    int kc = z - e * a.KS;
    if constexpr (EXPERT) {
      int o0 = a.off[e], o1 = a.off[e + 1];
      if ((int)blockIdx.y * TM >= o1 - o0) return;  // early-exit before any barrier
      m0 = o0 + blockIdx.y * TM;
      sEnd = o1;
      Bb += (long)e * a.sBz * 4 + (long)kc * a.zB;
      Ab += (long)kc * a.zA;
      AbL += (long)kc * a.zA;
    } else {
      m0 = blockIdx.y * TM;
      Ab += (long)e * a.sAz * 4 + (long)kc * a.zA;
      AbL += (long)kc * a.zA;
      Bb += (long)e * a.sBz * 4 + (long)kc * a.zB;
      if constexpr (CM == 0) {
        O += (long)e * a.sOz;
        if constexpr (SPL) OL += (long)e * a.sOz;
      }
    }
    if constexpr (CM == 4) HoutP += (long)kc * a.zH;
  }
  const int n0 = blockIdx.x * TN;

  // ---- rms prologue: rr per tile row from NP col-partials ----
  if constexpr (AM == 2 || AM == 3) {
    if (tid < TM) {
      int s = m0 + tid;
      int row = (AM == 3) ? a.perm[imin(s, a.M - 1)] : imin(s, a.M - 1);
      float ss = 0.f;
      #pragma unroll
      for (int j = 0; j < NP; ++j) ss += a.rspIn[row * NP + j];
      rrlds[tid] = rsqrtf(ss * (1.f / 768.f) + 1e-6f);
    }
  }

  int arow[UA];
  #pragma unroll
  for (int u = 0; u < UA; ++u) {
    int id = tid + u * NT;
    if constexpr (AM == 0) arow[u] = imin(m0 + (id >> 3), a.M - 1);
    else if constexpr (AM == 3) arow[u] = a.perm[imin(m0 + (id >> 4), a.M - 1)];
    else if constexpr (AM == 4) arow[u] = id % TM;   // local col in source
    else arow[u] = imin(m0 + (id >> 4), a.M - 1);
  }

  using ARt = typename std::conditional<AM == 0, int4, float4>::type;
  using BRt = typename std::conditional<BMD == 0, int4, float4>::type;

  auto issueA = [&](ARt* rg, ARt* rl, int k0) {
    #pragma unroll
    for (int u = 0; u < UA; ++u) {
      int id = tid + u * NT;
      if constexpr (AM == 0) {
        int kq = id & 7;
        long off = ((long)arow[u] * a.lda + k0 + kq * 8) * 2;
        rg[u] = *(const int4*)(Ab + off);
        if constexpr (SPL) rl[u] = *(const int4*)(AbL + off);
      } else if constexpr (AM == 4) {
        int kq = id / TM;
        const float* g = (const float*)Ab;
        #pragma unroll
        for (int i = 0; i < 4; ++i)
          ((float*)&rg[u])[i] = g[(long)(k0 + kq * 4 + i) * a.lda + (m0 + arow[u])];
      } else {
        int kq = id & 15;
        rg[u] = *(const float4*)(Ab + ((long)arow[u] * a.lda + k0 + kq * 4) * 4);
      }
    }
  };
  auto commitA = [&](ARt* rg, ARt* rl, int k0, int bi) {
    char* base = (char*)As + bi * (TM * 128);
    char* baseL = (char*)AsL + (SPL ? bi * (TM * 128) : 0);
    #pragma unroll
    for (int u = 0; u < UA; ++u) {
      int id = tid + u * NT;
      if constexpr (AM == 0) {
        int m = id >> 3, kq = id & 7;
        *(int4*)(base + swz(m, kq * 16)) = rg[u];
        if constexpr (SPL) *(int4*)(baseL + swz(m, kq * 16)) = rl[u];
      } else {
        int m, kq;
        if constexpr (AM == 4) { m = id % TM; kq = id / TM; }
        else { m = id >> 4; kq = id & 15; }
        float4 v = *(float4*)&rg[u];
        if constexpr (AM == 2 || AM == 3) {
          float rr = rrlds[m];
          const float* w = a.lnw + k0 + kq * 4;
          v.x *= rr * w[0]; v.y *= rr * w[1]; v.z *= rr * w[2]; v.w *= rr * w[3];
        }
        if constexpr (SPL) {
          uint2 ph, pl;
          split2(v.x, v.y, ph.x, pl.x);
          split2(v.z, v.w, ph.y, pl.y);
          *(uint2*)(base + swz(m, kq * 8)) = ph;
          *(uint2*)(baseL + swz(m, kq * 8)) = pl;
        } else {
          uint2 p; unsigned t;
          split2(v.x, v.y, p.x, t); split2(v.z, v.w, p.y, t);
          *(uint2*)(base + swz(m, kq * 8)) = p;
        }
      }
    }
  };
  auto issueB = [&](BRt* rg, BRt* rl, int k0) {
    #pragma unroll
    for (int u = 0; u < UB; ++u) {
      int id = tid + u * NT;
      if constexpr (BMD == 0) {
        int n = id >> 3, kq = id & 7;
        long off = ((long)(n0 + n) * a.ldb + k0 + kq * 8) * 2;
        rg[u] = *(const int4*)(Bb + off);
        if constexpr (SPL) rl[u] = *(const int4*)(BbL + off);
      } else if constexpr (BMD == 1) {
        int n = id % TN, kq = id / TN;
        const float* g = (const float*)Bb;
        #pragma unroll
        for (int i = 0; i < 4; ++i)
          ((float*)&rg[u])[i] = g[(long)(k0 + kq * 4 + i) * a.ldb + (n0 + n)];
      } else {
        int n = id >> 4, kq = id & 15;
        rg[u] = *(const float4*)(Bb + ((long)(n0 + n) * a.ldb + k0 + kq * 4) * 4);
      }
    }
  };
  auto commitB = [&](BRt* rg, BRt* rl, int bi) {
    char* base = (char*)Bs + bi * (TN * 128);
    char* baseL = (char*)BsL + (SPL ? bi * (TN * 128) : 0);
    #pragma unroll
    for (int u = 0; u < UB; ++u) {
      int id = tid + u * NT;
      if constexpr (BMD == 0) {
        int n = id >> 3, kq = id & 7;
        *(int4*)(base + swz(n, kq * 16)) = rg[u];
        if constexpr (SPL) *(int4*)(baseL + swz(n, kq * 16)) = rl[u];
      } else {
        int n, kq;
        if constexpr (BMD == 1) { n = id % TN; kq = id / TN; }
        else { n = id >> 4; kq = id & 15; }
        float4 v = *(float4*)&rg[u];
        if constexpr (SPL) {
          uint2 ph, pl;
          split2(v.x, v.y, ph.x, pl.x);
          split2(v.z, v.w, ph.y, pl.y);
          *(uint2*)(base + swz(n, kq * 8)) = ph;
          *(uint2*)(baseL + swz(n, kq * 8)) = pl;
        } else {
          uint2 p; unsigned t;
          split2(v.x, v.y, p.x, t); split2(v.z, v.w, p.y, t);
          *(uint2*)(base + swz(n, kq * 8)) = p;
        }
      }
    }
  };

  f32x4 acc[FM][FN] = {};
  auto compute = [&](int bi) {
    const char* pA = (const char*)As + bi * (TM * 128);
    const char* pAL = (const char*)AsL + (SPL ? bi * (TM * 128) : 0);
    const char* pB = (const char*)Bs + bi * (TN * 128);
    const char* pBL = (const char*)BsL + (SPL ? bi * (TN * 128) : 0);
    #pragma unroll
    for (int kk = 0; kk < 2; ++kk) {
      const int col2 = (kk * 32 + (lane >> 4) * 8) * 2;
      f16x8 ah[FM], bh[FN];
      #pragma unroll
      for (int i = 0; i < FM; ++i)
        ah[i] = *(const f16x8*)(pA + swz(wr * WTM + i * 16 + (lane & 15), col2));
      #pragma unroll
      for (int j = 0; j < FN; ++j)
        bh[j] = *(const f16x8*)(pB + swz(wc * WTN + j * 16 + (lane & 15), col2));
      if constexpr (SPL) {
        f16x8 al[FM], bl[FN];
        #pragma unroll
        for (int i = 0; i < FM; ++i)
          al[i] = *(const f16x8*)(pAL + swz(wr * WTM + i * 16 + (lane & 15), col2));
        #pragma unroll
        for (int j = 0; j < FN; ++j)
          bl[j] = *(const f16x8*)(pBL + swz(wc * WTN + j * 16 + (lane & 15), col2));
        #pragma unroll
        for (int i = 0; i < FM; ++i)
          #pragma unroll
          for (int j = 0; j < FN; ++j) {
            f32x4 t = acc[i][j];
            t = __builtin_amdgcn_mfma_f32_16x16x32_f16(al[i], bh[j], t, 0, 0, 0);
            t = __builtin_amdgcn_mfma_f32_16x16x32_f16(ah[i], bl[j], t, 0, 0, 0);
            t = __builtin_amdgcn_mfma_f32_16x16x32_f16(ah[i], bh[j], t, 0, 0, 0);
            acc[i][j] = t;
          }
      } else {
        #pragma unroll
        for (int i = 0; i < FM; ++i)
          #pragma unroll
          for (int j = 0; j < FN; ++j)
            acc[i][j] = __builtin_amdgcn_mfma_f32_16x16x32_f16(ah[i], bh[j], acc[i][j], 0, 0, 0);
      }
    }
  };

  // ---- main loop: 3 register sets (depth-2 prefetch), 2 LDS buffers, 1 barrier/step ----
  ARt ag0[UA], ag1[UA], ag2[UA], al0[UA], al1[UA], al2[UA];
  BRt bg0[UB], bg1[UB], bg2[UB], bl0[UB], bl1[UB], bl2[UB];
  const int ns = a.K / TK;
  issueA(ag0, al0, 0); issueB(bg0, bl0, 0);
  if (TK < a.K) { issueA(ag1, al1, TK); issueB(bg1, bl1, TK); }
  __syncthreads();  // covers rrlds
  for (int s = 0; s < ns; s += 6) {
    int k;
    { commitA(ag0, al0, (s + 0) * TK, 0); commitB(bg0, bl0, 0);
      k = (s + 2) * TK; if (k < a.K) { issueA(ag2, al2, k); issueB(bg2, bl2, k); }
      __syncthreads(); compute(0); }
    if (s + 1 < ns) {
      commitA(ag1, al1, (s + 1) * TK, 1); commitB(bg1, bl1, 1);
      k = (s + 3) * TK; if (k < a.K) { issueA(ag0, al0, k); issueB(bg0, bl0, k); }
      __syncthreads(); compute(1); }
    if (s + 2 < ns) {
      commitA(ag2, al2, (s + 2) * TK, 0); commitB(bg2, bl2, 0);
      k = (s + 4) * TK; if (k < a.K) { issueA(ag1, al1, k); issueB(bg1, bl1, k); }
      __syncthreads(); compute(0); }
    if (s + 3 < ns) {
      commitA(ag0, al0, (s + 3) * TK, 1); commitB(bg0, bl0, 1);
      k = (s + 5) * TK; if (k < a.K) { issueA(ag2, al2, k); issueB(bg2, bl2, k); }
      __syncthreads(); compute(1); }
    if (s + 4 < ns) {
      commitA(ag1, al1, (s + 4) * TK, 0); commitB(bg1, bl1, 0);
      k = (s + 6) * TK; if (k < a.K) { issueA(ag0, al0, k); issueB(bg0, bl0, k); }
      __syncthreads(); compute(0); }
    if (s + 5 < ns) {
      commitA(ag2, al2, (s + 5) * TK, 1); commitB(bg2, bl2, 1);
      k = (s + 7) * TK; if (k < a.K) { issueA(ag1, al1, k); issueB(bg1, bl1, k); }
      __syncthreads(); compute(1); }
  }

  // ---- epilogue ----
  const int cr = (lane >> 4) * 4;
  const int cc = lane & 15;
  if constexpr (CM == 0 || CM == 2) {
    #pragma unroll
    for (int i = 0; i < FM; ++i) {
      #pragma unroll
      for (int r = 0; r < 4; ++r) {
        int gm = m0 + wr * WTM + i * 16 + cr + r;
        if (gm >= sEnd) continue;
        #pragma unroll
        for (int j = 0; j < FN; ++j) {
          int gn = n0 + wc * WTN + j * 16 + cc;
          float v = acc[i][j][r];
          if constexpr (CM == 2) v = fmaxf(v, 0.f);
          f16 hv = (f16)v;
          O[(long)gm * a.ldo + gn] = hv;
          if constexpr (SPL) OL[(long)gm * a.ldo + gn] = (f16)(v - (float)hv);
        }
      }
    }
  } else if constexpr (CM == 4) {
    #pragma unroll
    for (int i = 0; i < FM; ++i) {
      #pragma unroll
      for (int r = 0; r < 4; ++r) {
        int s = m0 + wr * WTM + i * 16 + cr + r;
        if (s >= sEnd || s >= a.M) continue;
        #pragma unroll
        for (int j = 0; j < FN; ++j) {
          int gn = n0 + wc * WTN + j * 16 + cc;
          HoutP[(long)s * a.ldo + gn] = acc[i][j][r];
        }
      }
    }
  } else {
    #pragma unroll
    for (int i = 0; i < FM; ++i) {
      #pragma unroll
      for (int r = 0; r < 4; ++r) {
        int s = m0 + wr * WTM + i * 16 + cr + r;
        int grow = s;
        float p = 1.f;
        bool ok = true;
        if constexpr (CM == 3) {
          ok = s < sEnd;
          int t = a.perm[imin(s, a.M - 1)];
          grow = t;
          p = a.prob[t];
        }
        #pragma unroll
        for (int j = 0; j < FN; ++j) {
          int gn = n0 + wc * WTN + j * 16 + cc;
          float v = acc[i][j][r];
          if constexpr (CM == 3) v *= p;
          if constexpr (BIAS) v += a.bias[gn];
          if constexpr (RESID) v += a.Hin[(long)grow * 768 + gn];
          if constexpr (CM == 3) v += a.Hin[(long)grow * 768 + gn];
          if (ok) a.Hout[(long)grow * 768 + gn] = v;
          float ssum = v * v;
          ssum += __shfl_xor(ssum, 1); ssum += __shfl_xor(ssum, 2);
          ssum += __shfl_xor(ssum, 4); ssum += __shfl_xor(ssum, 8);
          if (ok && (lane & 15) == 0)
            a.rspOut[(long)grow * NP + ((n0 + wc * WTN + j * 16) >> 4)] = ssum;
        }
      }
    }
  }
}

// ---- split-K reduce: out[row] = p*(s0+s1+s2+s3) [+bias] [+Hin[row]], + rsum partials ----
__global__ __launch_bounds__(256)
void red_k(const float* slab, long sst, const int* perm, const float* prob,
           const float* Hin, const float* bias, float* Hout, float* rsp) {
  int lane = threadIdx.x & 63;
  int s = blockIdx.x * 4 + (threadIdx.x >> 6);
  int row = perm ? perm[s] : s;
  float p = prob ? prob[row] : 1.f;
  #pragma unroll
  for (int p3 = 0; p3 < 3; ++p3) {
    int c = p3 * 256 + lane * 4;
    float4 v = *(const float4*)(slab + (long)s * 768 + c);
    float4 v1 = *(const float4*)(slab + sst + (long)s * 768 + c);
    float4 v2 = *(const float4*)(slab + 2 * sst + (long)s * 768 + c);
    float4 v3 = *(const float4*)(slab + 3 * sst + (long)s * 768 + c);
    v.x = (v.x + v1.x) + (v2.x + v3.x); v.y = (v.y + v1.y) + (v2.y + v3.y);
    v.z = (v.z + v1.z) + (v2.z + v3.z); v.w = (v.w + v1.w) + (v2.w + v3.w);
    v.x *= p; v.y *= p; v.z *= p; v.w *= p;
    if (bias) {
      const float4 b = *(const float4*)(bias + c);
      v.x += b.x; v.y += b.y; v.z += b.z; v.w += b.w;
    }
    if (Hin) {
      const float4 h = *(const float4*)(Hin + (long)row * 768 + c);
      v.x += h.x; v.y += h.y; v.z += h.z; v.w += h.w;
    }
    *(float4*)(Hout + (long)row * 768 + c) = v;
    float ss = v.x * v.x + v.y * v.y + v.z * v.z + v.w * v.w;
    ss += __shfl_xor(ss, 1); ss += __shfl_xor(ss, 2);
    if ((lane & 3) == 0) rsp[(long)row * NP + p3 * 16 + (lane >> 2)] = ss;
  }
}

// ---- router: one wave per row ----
__global__ __launch_bounds__(256)
void router_k(const float* H, const float* rsp, const float* lnw, const float* rw,
              int* eid, float* prob) {
  int lane = threadIdx.x & 63;
  int row = blockIdx.x * 4 + (threadIdx.x >> 6);
  float ss = 0.f;
  #pragma unroll
  for (int j = 0; j < NP; ++j) ss += rsp[row * NP + j];
  float rr = rsqrtf(ss * (1.f / 768.f) + 1e-6f);
  float le[8] = {0, 0, 0, 0, 0, 0, 0, 0};
  #pragma unroll
  for (int i = 0; i < 12; ++i) {
    int k = i * 64 + lane;
    float n = H[row * 768 + k] * rr * lnw[k];
    const float* w = rw + k * 8;
    float4 w0 = *(const float4*)w, w1 = *(const float4*)(w + 4);
    le[0] += n * w0.x; le[1] += n * w0.y; le[2] += n * w0.z; le[3] += n * w0.w;
    le[4] += n * w1.x; le[5] += n * w1.y; le[6] += n * w1.z; le[7] += n * w1.w;
  }
  #pragma unroll
  for (int m = 1; m < 64; m <<= 1) {
    #pragma unroll
    for (int e = 0; e < 8; ++e) le[e] += __shfl_xor(le[e], m);
  }
  float mx = le[0]; int am = 0;
  #pragma unroll
  for (int e = 1; e < 8; ++e) if (le[e] > mx) { mx = le[e]; am = e; }
  float den = 0.f;
  #pragma unroll
  for (int e = 0; e < 8; ++e) den += expf(le[e] - mx);
  if (lane == 0) { eid[row] = am; prob[row] = 1.f / den; }
}

__global__ __launch_bounds__(256)
void scan_k(const int* eid, int* off, int* perm) {
  __shared__ int cnt[8], c2[8], offs[9];
  int tid = threadIdx.x;
  if (tid < 8) { cnt[tid] = 0; c2[tid] = 0; }
  __syncthreads();
  for (int t = tid; t < 1024; t += 256) atomicAdd(&cnt[eid[t]], 1);
  __syncthreads();
  if (tid == 0) {
    int acc = 0;
    for (int e = 0; e < 8; ++e) { offs[e] = acc; acc += cnt[e]; }
    offs[8] = acc;
    for (int e = 0; e < 9; ++e) off[e] = offs[e];
  }
  __syncthreads();
  for (int t = tid; t < 1024; t += 256) {
    int e = eid[t];
    int r = atomicAdd(&c2[e], 1);
    perm[offs[e] + r] = t;
  }
}

__global__ __launch_bounds__(256)
void fc_k(const float* H, const float* rsp, const float* lnw, const float* fw,
          const float* fb, float* out) {
  int lane = threadIdx.x & 63;
  int row = blockIdx.x * 4 + (threadIdx.x >> 6);
  float ss = 0.f;
  #pragma unroll
  for (int j = 0; j < NP; ++j) ss += rsp[row * NP + j];
  float rr = rsqrtf(ss * (1.f / 768.f) + 1e-6f);
  float acc[10] = {0, 0, 0, 0, 0, 0, 0, 0, 0, 0};
  #pragma unroll
  for (int i = 0; i < 12; ++i) {
    int k = i * 64 + lane;
    float n = H[row * 768 + k] * rr * lnw[k];
    const float* w = fw + k * 10;
    #pragma unroll
    for (int c = 0; c < 10; ++c) acc[c] += n * w[c];
  }
  #pragma unroll
  for (int m = 1; m < 64; m <<= 1) {
    #pragma unroll
    for (int c = 0; c < 10; ++c) acc[c] += __shfl_xor(acc[c], m);
  }
  if (lane == 0) {
    #pragma unroll
    for (int c = 0; c < 10; ++c) out[row * 10 + c] = acc[c] + fb[c];
  }
}

extern "C" void kernel_launch(void* const* d_in, const int* in_sizes, int n_in,
                              void* d_out, int out_size, void* d_ws, size_t ws_size,
                              hipStream_t stream) {
  const float* x     = (const float*)d_in[0];
  const float* projw = (const float*)d_in[1];
  const float* projb = (const float*)d_in[2];
  const float* ln1   = (const float*)d_in[3];
  const float* wvp   = (const float*)d_in[4];
  const float* wop   = (const float*)d_in[5];
  const float* ln2   = (const float*)d_in[6];
  const float* dwi   = (const float*)d_in[7];
  const float* dwo   = (const float*)d_in[8];
  const float* rw    = (const float*)d_in[9];
  const float* ewi   = (const float*)d_in[10];
  const float* ewo   = (const float*)d_in[11];
  const float* flnw  = (const float*)d_in[12];
  const float* fcw   = (const float*)d_in[13];
  const float* fcb   = (const float*)d_in[14];

  char* ws = (char*)d_ws;
  float* hA   = (float*)(ws);                        // 3,145,728
  float* hB   = (float*)(ws + 3145728);              // 3,145,728
  f16*   hidH = (f16*)(ws + 6291456);                // 6,291,456
  f16*   hidL = (f16*)(ws + 12582912);               // 6,291,456
  float* rsp  = (float*)(ws + 18874368);             // 25*1024*48*4 = 4,915,200
  int*   eid  = (int*)(ws + 23789568);
  float* prob = (float*)(ws + 23793664);
  int*   perm = (int*)(ws + 23797760);
  int*   off  = (int*)(ws + 23801856);
  float* slab = (float*)(ws + 23802368);             // 4*1024*768*4 = 12,582,912
  f16*   wctH = (f16*)(ws + 36385280);               // 14,155,776
  f16*   wctL = (f16*)(ws + 50541056);               // 14,155,776 -> end 64,696,832
  if (ws_size < 36385280u) return;
  const bool useWct = ws_size >= 64696832u;
  auto slot = [&](int s) { return rsp + (long)s * 1024 * NP; };
  const long SST = 1024 * 768;

  if (useWct) {  // Wc^T[l] = (wv@wo)^T as f16 hi/lo pair: wct[l][n][k]
    GArgs g{}; g.A = wop; g.B = wvp; g.O16 = wctH; g.O16lo = wctL; g.KS = 1;
    g.M = 768; g.K = 768; g.lda = 768; g.ldb = 768; g.ldo = 768;
    g.sAz = 589824; g.sBz = 589824; g.sOz = 589824;
    gk<32,64,2,2, 4,2,0, false,false,false,true><<<dim3(12,24,12), 256, 0, stream>>>(g);
  }
  { // proj split-K=4: slab[kc] = x[:, kc] @ proj_w[kc, :]
    GArgs g{}; g.A = x; g.B = projw; g.Hout = slab; g.KS = 4;
    g.M = 1024; g.K = 768; g.lda = 3072; g.ldb = 768; g.ldo = 768;
    g.zA = 768 * 4; g.zB = (long)768 * 768 * 4; g.zH = SST;
    gk<32,64,2,2, 1,1,4, false,false,false,true><<<dim3(12,32,4), 256, 0, stream>>>(g);
    red_k<<<dim3(256), 256, 0, stream>>>(slab, SST, nullptr, nullptr, nullptr, projb, hA, slot(0));
  }
  for (int l = 0; l < 12; ++l) {
    if (useWct) { // attn: hB = hA + rmsnorm(hA,ln1) @ Wc[l]
      GArgs g{}; g.A = hA; g.B = wctH + (long)l * 589824; g.Blo = wctL + (long)l * 589824;
      g.Hin = hA; g.Hout = hB; g.KS = 1;
      g.rspIn = slot(2*l); g.rspOut = slot(2*l+1); g.lnw = ln1 + l * 768;
      g.M = 1024; g.K = 768; g.lda = 768; g.ldb = 768;
      gk<32,32,2,2, 2,0,1, true,false,false,true><<<dim3(24,32,1), 256, 0, stream>>>(g);
    } else {
      { // t = rmsnorm(hA,ln1) @ wv -> hid pair
        GArgs g{}; g.A = hA; g.B = wvp + (long)l * 589824; g.O16 = hidH; g.O16lo = hidL;
        g.rspIn = slot(2*l); g.lnw = ln1 + l * 768; g.KS = 1;
        g.M = 1024; g.K = 768; g.lda = 768; g.ldb = 768; g.ldo = 768;
        gk<32,64,2,2, 2,1,0, false,false,false,true><<<dim3(12,32,1), 256, 0, stream>>>(g);
      }
      { // hB = hA + t @ wo
        GArgs g{}; g.A = hidH; g.Alo = hidL; g.B = wop + (long)l * 589824;
        g.Hin = hA; g.Hout = hB; g.rspOut = slot(2*l+1); g.KS = 1;
        g.M = 1024; g.K = 768; g.lda = 768; g.ldb = 768;
        gk<32,64,2,2, 0,1,1, true,false,false,true><<<dim3(12,32,1), 256, 0, stream>>>(g);
      }
    }
    if ((l & 1) == 0) {
      int di = l / 2;
      { // ffn1: hid pair = relu(rmsnorm(hB,ln2) @ dwi)
        GArgs g{}; g.A = hB; g.B = dwi + (long)di * 768 * 3072; g.O16 = hidH; g.O16lo = hidL;
        g.rspIn = slot(2*l+1); g.lnw = ln2 + l * 768; g.KS = 1;
        g.M = 1024; g.K = 768; g.lda = 768; g.ldb = 3072; g.ldo = 3072;
        gk<32,64,2,2, 2,1,2, false,false,false,true><<<dim3(48,32,1), 256, 0, stream>>>(g);
      }
      { // ffn2 split-K=4 into slabs
        GArgs g{}; g.A = hidH; g.Alo = hidL; g.B = dwo + (long)di * 3072 * 768;
        g.Hout = slab; g.KS = 4;
        g.M = 1024; g.K = 768; g.lda = 3072; g.ldb = 768; g.ldo = 768;
        g.zA = 768 * 2; g.zB = (long)768 * 768 * 4; g.zH = SST;
        gk<32,64,2,2, 0,1,4, false,false,false,true><<<dim3(12,32,4), 256, 0, stream>>>(g);
        red_k<<<dim3(256), 256, 0, stream>>>(slab, SST, nullptr, nullptr, hB, nullptr, hA, slot(2*l+2));
      }
    } else {
      int mi = l / 2;
      router_k<<<dim3(256), 256, 0, stream>>>(hB, slot(2*l+1), ln2 + l * 768,
                                              rw + (long)mi * 768 * 8, eid, prob);
      scan_k<<<dim3(1), 256, 0, stream>>>(eid, off, perm);
      { // egemm1: hid[slot] pair = relu(rmsnorm(hB)[perm[slot]] @ ewi[e])
        GArgs g{}; g.A = hB; g.B = ewi + (long)mi * 8 * 768 * 3072; g.O16 = hidH; g.O16lo = hidL;
        g.rspIn = slot(2*l+1); g.lnw = ln2 + l * 768; g.perm = perm; g.off = off; g.KS = 1;
        g.M = 1024; g.K = 768; g.lda = 768; g.ldb = 3072; g.ldo = 3072;
        g.sBz = (long)768 * 3072;
        gk<64,32,2,2, 3,1,2, false,false,true,true><<<dim3(96,16,8), 256, 0, stream>>>(g);
      }
      { // egemm2 split-K=4: slab[kc][slot] = hid[slot, kc] @ ewo[e][kc, :]
        GArgs g{}; g.A = hidH; g.Alo = hidL; g.B = ewo + (long)mi * 8 * 3072 * 768;
        g.Hout = slab; g.off = off; g.KS = 4;
        g.M = 1024; g.K = 768; g.lda = 3072; g.ldb = 768; g.ldo = 768;
        g.sBz = (long)3072 * 768; g.zA = 768 * 2; g.zB = (long)768 * 768 * 4; g.zH = SST;
        gk<32,64,2,2, 0,1,4, false,false,true,true><<<dim3(12,32,32), 256, 0, stream>>>(g);
        red_k<<<dim3(256), 256, 0, stream>>>(slab, SST, perm, prob, hB, nullptr, hA, slot(2*l+2));
      }
    }
  }
  fc_k<<<dim3(256), 256, 0, stream>>>(hA, slot(24), flnw, fcw, fcb, (float*)d_out);
}